// Round 3
// baseline (112.653 us; speedup 1.0000x reference)
//
#include <hip/hip_runtime.h>
#include <math.h>

#define BB 4
#define HH 512
#define WW 512
#define HWSZ (HH * WW)

#define TCOLS 8     // columns per block
#define TCH   32    // row-chunks per block
#define CROWS 16    // rows per chunk (TCH*CROWS == HH)
#define NBLK_COLS (BB * (WW / TCOLS))   // 256
#define NBLK_ROWS (BB * HH)             // 2048
#define NSLOTS 32                       // 8 accumulator slots per batch

// ws layout:
//   [0,    1024)   int counts[256]     (one per edt_cols block; all written)
//   [1024, 1280)   double slots[32]    (zeroed by edt_cols block 0)
//   [1536, 1540)   int ticket          (zeroed by edt_cols block 0)
//   [32768, +4MB)  u32 gpack[BB*HH*WW] (low16 = g seed=mask, high16 = g seed=~mask)

// ---------------------------------------------------------------------------
// Pass 1: per-column 1D nearest-seed distances for BOTH seeds via a
// block-level segmented scan. Thread (c, ch) owns 16 rows of one column,
// packs the mask into a u16 bitfield (in u32); chunk summaries go to LDS; an
// 8-thread 32-step scan yields chunk-boundary prefixes; per-row distances
// come from clz/ctz on the register bitmask. 16 independent loads/thread,
// 256 blocks = 1024 waves for latency hiding. Block 0 also zeroes the
// accumulator slots + ticket used by the fused reduction in pass 2.
// ---------------------------------------------------------------------------
__global__ __launch_bounds__(256) void edt_cols_kernel(
    const int* __restrict__ target,
    unsigned int* __restrict__ gpack,
    int* __restrict__ counts,
    double* __restrict__ slots,
    int* __restrict__ ticket)
{
    int blk = blockIdx.x;          // b*64 + tile
    int b = blk >> 6;
    int tile = blk & 63;
    int tid = threadIdx.x;
    int c = tid & (TCOLS - 1);     // column within tile
    int ch = tid >> 3;             // chunk index (0..31)
    int j = tile * TCOLS + c;
    int r0 = ch * CROWS;

    if (blk == 0) {                // init for pass-2 fused reduction
        if (tid < NSLOTS) slots[tid] = 0.0;
        if (tid == NSLOTS) *ticket = 0;
    }

    const int* t = target + b * HWSZ + j;

    unsigned int maskN = 0;        // 16 independent loads -> row bitmask
#pragma unroll
    for (int i = 0; i < CROWS; ++i)
        maskN |= (unsigned int)(t[(r0 + i) * WW] == 1) << i;
    unsigned int maskP = maskN ^ 0xFFFFu;

    __shared__ short sLastN[TCH][TCOLS], sLastP[TCH][TCOLS];
    __shared__ short sFirstN[TCH][TCOLS], sFirstP[TCH][TCOLS];
    __shared__ short sBefN[TCH][TCOLS], sBefP[TCH][TCOLS];
    __shared__ short sAftN[TCH][TCOLS], sAftP[TCH][TCOLS];
    __shared__ int sCnt;

    sLastN[ch][c]  = maskN ? (short)(r0 + 31 - __builtin_clz(maskN)) : (short)-1;
    sFirstN[ch][c] = maskN ? (short)(r0 + __builtin_ctz(maskN))      : (short)-1;
    sLastP[ch][c]  = maskP ? (short)(r0 + 31 - __builtin_clz(maskP)) : (short)-1;
    sFirstP[ch][c] = maskP ? (short)(r0 + __builtin_ctz(maskP))      : (short)-1;
    if (tid == 0) sCnt = 0;
    __syncthreads();

    if (tid < TCOLS) {             // one thread per column: 32-step chunk scan
        short befN = -1, befP = -1;
        for (int k = 0; k < TCH; ++k) {
            sBefN[k][tid] = befN; sBefP[k][tid] = befP;
            short ln = sLastN[k][tid], lp = sLastP[k][tid];
            if (ln >= 0) befN = ln;
            if (lp >= 0) befP = lp;
        }
        short aftN = -1, aftP = -1;
        for (int k = TCH - 1; k >= 0; --k) {
            sAftN[k][tid] = aftN; sAftP[k][tid] = aftP;
            short fn = sFirstN[k][tid], fp = sFirstP[k][tid];
            if (fn >= 0) aftN = fn;
            if (fp >= 0) aftP = fp;
        }
    }
    atomicAdd(&sCnt, __popc(maskN));
    __syncthreads();

    int befN = sBefN[ch][c], befP = sBefP[ch][c];
    int aftN = sAftN[ch][c], aftP = sAftP[ch][c];
    unsigned int* gp = gpack + b * HWSZ + j;

#pragma unroll
    for (int i = 0; i < CROWS; ++i) {
        int row = r0 + i;
        unsigned int belowN = maskN << (31 - i);   // bit31 = row i
        unsigned int aboveN = maskN >> i;          // bit0  = row i
        unsigned int dfN = belowN ? (unsigned int)__builtin_clz(belowN)
                                  : (befN >= 0 ? (unsigned int)(row - befN) : 0xFFFFu);
        unsigned int dbN = aboveN ? (unsigned int)__builtin_ctz(aboveN)
                                  : (aftN >= 0 ? (unsigned int)(aftN - row) : 0xFFFFu);
        unsigned int gN = dfN < dbN ? dfN : dbN;

        unsigned int belowP = maskP << (31 - i);
        unsigned int aboveP = maskP >> i;
        unsigned int dfP = belowP ? (unsigned int)__builtin_clz(belowP)
                                  : (befP >= 0 ? (unsigned int)(row - befP) : 0xFFFFu);
        unsigned int dbP = aboveP ? (unsigned int)__builtin_ctz(aboveP)
                                  : (aftP >= 0 ? (unsigned int)(aftP - row) : 0xFFFFu);
        unsigned int gP = dfP < dbP ? dfP : dbP;

        gp[row * WW] = gN | (gP << 16);
    }

    if (tid == 0) counts[blk] = sCnt;
}

// ---------------------------------------------------------------------------
// Pass 2 (fused with final reduction): exact row lower-envelope
// d2(j) = min_k g2[k] + (j-k)^2 for both maps via expanding-ring search with
// early exit (exact: once r^2 >= both current bests no farther k can
// improve). dmap = sqrt(d2n)-sqrt(d2p), weighted by p1 = sigmoid(x1-x0).
// Block partial: wave shuffle-reduce + one f64 atomic into a contention-
// spread slot. A ticket elects the last block to apply the per-batch
// presence guard and write out[0].
// ---------------------------------------------------------------------------
__global__ __launch_bounds__(256) void edt_rows_kernel(
    const unsigned int* __restrict__ gpack,
    const float* __restrict__ pred,
    const int* __restrict__ counts,
    double* __restrict__ slots,
    int* __restrict__ ticket,
    float* __restrict__ out)
{
    __shared__ float g2n[WW];
    __shared__ float g2p[WW];
    __shared__ double wred[4];
    __shared__ int isLast;
    __shared__ int sPres[BB];
    __shared__ double sSum[NSLOTS];

    int bi = blockIdx.x;            // b*HH + i
    int b = bi >> 9;
    int i = bi & (HH - 1);
    int tid = threadIdx.x;

    const unsigned int* gp = gpack + b * HWSZ + i * WW;
    for (int k = tid; k < WW; k += 256) {
        unsigned int pk = gp[k];
        unsigned int gN = pk & 0xFFFFu;
        unsigned int gP = pk >> 16;
        g2n[k] = (gN == 0xFFFFu) ? 1e18f : (float)(gN * gN);
        g2p[k] = (gP == 0xFFFFu) ? 1e18f : (float)(gP * gP);
    }
    if (tid < BB) sPres[tid] = 0;
    __syncthreads();

    const float* p0 = pred + (b * 2 + 0) * HWSZ + i * WW;
    const float* p1 = pred + (b * 2 + 1) * HWSZ + i * WW;

    float local = 0.0f;
    for (int j = tid; j < WW; j += 256) {
        float bn = g2n[j];
        float bp = g2p[j];
        for (int r = 1; r < WW; ++r) {
            float sq = (float)(r * r);
            if (sq >= bn && sq >= bp) break;
            int kl = j - r;
            int kr = j + r;
            if (kl >= 0) {
                bn = fminf(bn, sq + g2n[kl]);
                bp = fminf(bp, sq + g2p[kl]);
            }
            if (kr < WW) {
                bn = fminf(bn, sq + g2n[kr]);
                bp = fminf(bp, sq + g2p[kr]);
            }
        }
        float dist = sqrtf(bn) - sqrtf(bp);               // negEDT - posEDT
        float prob = 1.0f / (1.0f + __expf(p0[j] - p1[j]));  // softmax class-1
        local += prob * dist;
    }

    // wave-level shuffle reduction (64 lanes), then cross-wave via LDS
#pragma unroll
    for (int off = 32; off > 0; off >>= 1)
        local += __shfl_down(local, off, 64);
    if ((tid & 63) == 0) wred[tid >> 6] = (double)local;
    __syncthreads();

    if (tid == 0) {
        double partial = wred[0] + wred[1] + wred[2] + wred[3];
        atomicAdd(&slots[b * 8 + (bi & 7)], partial);
        __threadfence();
        int old = atomicAdd(ticket, 1);
        isLast = (old == NBLK_ROWS - 1);
    }
    __syncthreads();

    if (isLast) {
        // all other blocks' slot atomics happened-before their ticket
        // increments (threadfence); read slots coherently via atomic RMW.
        if (counts[tid] > 0) atomicOr(&sPres[tid >> 6], 1);  // 64 blocks/batch
        if (tid < NSLOTS) sSum[tid] = atomicAdd(&slots[tid], 0.0);
        __syncthreads();
        if (tid == 0) {
            double tot = 0.0;
            for (int bb = 0; bb < BB; ++bb) {
                double s = 0.0;
                for (int k = 0; k < 8; ++k) s += sSum[bb * 8 + k];
                if (sPres[bb]) tot += s;   // 'if mask.sum() > 0' guard
            }
            out[0] = (float)(tot * (1.0 / 2097152.0));  // mean over B*C*H*W
        }
    }
}

extern "C" void kernel_launch(void* const* d_in, const int* in_sizes, int n_in,
                              void* d_out, int out_size, void* d_ws, size_t ws_size,
                              hipStream_t stream) {
    const float* pred = (const float*)d_in[0];
    const int* target = (const int*)d_in[1];
    float* out = (float*)d_out;

    char* ws = (char*)d_ws;
    int* counts = (int*)(ws + 0);
    double* slots = (double*)(ws + 1024);
    int* ticket = (int*)(ws + 1536);
    unsigned int* gpack = (unsigned int*)(ws + 32768);

    edt_cols_kernel<<<NBLK_COLS, 256, 0, stream>>>(target, gpack, counts, slots, ticket);
    edt_rows_kernel<<<NBLK_ROWS, 256, 0, stream>>>(gpack, pred, counts, slots, ticket, out);
}

// Round 4
// 75.121 us; speedup vs baseline: 1.4996x; 1.4996x over previous
//
#include <hip/hip_runtime.h>
#include <math.h>

#define BB 4
#define HH 512
#define WW 512
#define HWSZ (HH * WW)

// ---- edt_cols tiling: 512 threads = TCOLS cols x TCH chunks, CROWS rows/chunk
#define TCOLS 16
#define TCH   32
#define CROWS 16
#define COLS_BLOCKS (BB * (WW / TCOLS))   // 128
#define ROWS_BLOCKS (BB * HH)             // 2048
#define BIGR 0x100000                     // "no seed" row sentinel for min-scans

// ws layout:
//   [0,    512)    int counts[128]       (one per edt_cols block; all written)
//   [1024, +16KB)  double partials[2048] (one per edt_rows block; all written)
//   [32768, +4MB)  u32 gpack[BB*HH*WW]   (low16 = g seed=mask, high16 = g seed=~mask)

// ---------------------------------------------------------------------------
// Pass 1: per-column 1D nearest-seed distances for BOTH seeds (mask, ~mask).
// Thread (c, ch) owns 16 rows of one column -> u16 row bitmask (16 independent
// loads for MLP). Chunk summaries (first/last seed row) to LDS; 8 waves run
// 5-step shuffle max/min scans (2 columns per wave, 32 chunks in 32 lanes) to
// get chunk-boundary prefixes; per-row distances via clz/ctz on the register
// mask. Mask count via wave popc-reduce (presence guard, no serial atomics).
// ---------------------------------------------------------------------------
__global__ __launch_bounds__(512) void edt_cols_kernel(
    const int* __restrict__ target,
    unsigned int* __restrict__ gpack,
    int* __restrict__ counts)
{
    int blk = blockIdx.x;          // b*32 + tile
    int b = blk >> 5;
    int tile = blk & 31;
    int tid = threadIdx.x;
    int c = tid & (TCOLS - 1);     // column within tile
    int ch = tid >> 4;             // chunk index 0..31
    int j = tile * TCOLS + c;
    int r0 = ch * CROWS;

    const int* t = target + b * HWSZ + j;

    unsigned int maskN = 0;        // 16 independent loads -> row bitmask
#pragma unroll
    for (int i = 0; i < CROWS; ++i)
        maskN |= (unsigned int)(t[(r0 + i) * WW] == 1) << i;
    unsigned int maskP = maskN ^ 0xFFFFu;

    __shared__ int sLN[TCH][TCOLS], sFN[TCH][TCOLS];   // last/first seed row
    __shared__ int sLP[TCH][TCOLS], sFP[TCH][TCOLS];
    __shared__ int sBN[TCH][TCOLS], sAN[TCH][TCOLS];   // before/after prefixes
    __shared__ int sBP[TCH][TCOLS], sAP[TCH][TCOLS];
    __shared__ int sCnt;

    sLN[ch][c] = maskN ? (r0 + 31 - __builtin_clz(maskN)) : -1;
    sFN[ch][c] = maskN ? (r0 + __builtin_ctz(maskN))      : BIGR;
    sLP[ch][c] = maskP ? (r0 + 31 - __builtin_clz(maskP)) : -1;
    sFP[ch][c] = maskP ? (r0 + __builtin_ctz(maskP))      : BIGR;

    int cnt = __popc(maskN);       // wave reduce, then one LDS atomic per wave
#pragma unroll
    for (int off = 32; off > 0; off >>= 1) cnt += __shfl_down(cnt, off, 64);
    if (tid == 0) sCnt = 0;
    __syncthreads();
    if ((tid & 63) == 0) atomicAdd(&sCnt, cnt);

    // shuffle scans: wave w handles columns 2w, 2w+1 (32 chunks in 32 lanes)
    int w = tid >> 6, lane = tid & 63;
    int cc = 2 * w + (lane >> 5);
    int c2 = lane & 31;            // chunk index inside the scan
    int iLN = sLN[c2][cc], iLP = sLP[c2][cc];
    int iFN = sFN[c2][cc], iFP = sFP[c2][cc];
#pragma unroll
    for (int d = 1; d < 32; d <<= 1) {          // inclusive forward max-scan
        int uLN = __shfl_up(iLN, d, 64);
        int uLP = __shfl_up(iLP, d, 64);
        if (c2 >= d) { iLN = max(iLN, uLN); iLP = max(iLP, uLP); }
    }
#pragma unroll
    for (int d = 1; d < 32; d <<= 1) {          // inclusive backward min-scan
        int dFN = __shfl_down(iFN, d, 64);
        int dFP = __shfl_down(iFP, d, 64);
        if (c2 + d < 32) { iFN = min(iFN, dFN); iFP = min(iFP, dFP); }
    }
    int bLN = __shfl_up(iLN, 1, 64);  if (c2 == 0)  bLN = -1;    // exclusive
    int bLP = __shfl_up(iLP, 1, 64);  if (c2 == 0)  bLP = -1;
    int aFN = __shfl_down(iFN, 1, 64); if (c2 == 31) aFN = BIGR;
    int aFP = __shfl_down(iFP, 1, 64); if (c2 == 31) aFP = BIGR;
    sBN[c2][cc] = bLN; sBP[c2][cc] = bLP;
    sAN[c2][cc] = aFN; sAP[c2][cc] = aFP;
    __syncthreads();

    int befN = sBN[ch][c], befP = sBP[ch][c];
    int aftN = sAN[ch][c], aftP = sAP[ch][c];
    unsigned int* gp = gpack + b * HWSZ + j;

#pragma unroll
    for (int i = 0; i < CROWS; ++i) {
        int row = r0 + i;
        unsigned int belowN = maskN << (31 - i);   // bit31 = row i
        unsigned int aboveN = maskN >> i;          // bit0  = row i
        unsigned int dfN = belowN ? (unsigned int)__builtin_clz(belowN)
                                  : (befN >= 0 ? (unsigned int)(row - befN) : 0xFFFFu);
        unsigned int dbN = aboveN ? (unsigned int)__builtin_ctz(aboveN)
                                  : (aftN < BIGR ? (unsigned int)(aftN - row) : 0xFFFFu);
        unsigned int gN = dfN < dbN ? dfN : dbN;
        if (gN > 0xFFFFu) gN = 0xFFFFu;

        unsigned int belowP = maskP << (31 - i);
        unsigned int aboveP = maskP >> i;
        unsigned int dfP = belowP ? (unsigned int)__builtin_clz(belowP)
                                  : (befP >= 0 ? (unsigned int)(row - befP) : 0xFFFFu);
        unsigned int dbP = aboveP ? (unsigned int)__builtin_ctz(aboveP)
                                  : (aftP < BIGR ? (unsigned int)(aftP - row) : 0xFFFFu);
        unsigned int gP = dfP < dbP ? dfP : dbP;
        if (gP > 0xFFFFu) gP = 0xFFFFu;

        gp[row * WW] = gN | (gP << 16);
    }

    if (tid == 0) counts[blk] = sCnt;
}

// ---------------------------------------------------------------------------
// Pass 2: one WAVE per image row. Lane k owns columns 8k..8k+7: pred loads
// are 4x float4 issued at entry (overlap staging), the exact expanding-ring
// search runs 8 columns interleaved (8-way LDS-load ILP, unified early-exit:
// extra iterations only add candidates >= the true min, so still exact).
// Out-of-range ring indices clamp to [0,511]: the clamped candidate
// r^2 + g2[edge] over-estimates a genuine candidate, so it cannot lower the
// min below the exact value. LDS skew j+(j>>5) keeps reads ~2-way (free).
// Reduction: 6 shuffles, one double store per block. No atomics, no fences.
// ---------------------------------------------------------------------------
#define SK(x) ((x) + ((x) >> 5))

__global__ __launch_bounds__(64) void edt_rows_kernel(
    const unsigned int* __restrict__ gpack,
    const float* __restrict__ pred,
    double* __restrict__ partials)
{
    __shared__ float g2n[SK(511) + 1];
    __shared__ float g2p[SK(511) + 1];

    int bi = blockIdx.x;            // b*HH + i
    int b = bi >> 9;
    int i = bi & (HH - 1);
    int k = threadIdx.x;            // lane 0..63
    int j0 = 8 * k;

    const float* p0 = pred + (b * 2 + 0) * HWSZ + i * WW + j0;
    const float* p1 = pred + (b * 2 + 1) * HWSZ + i * WW + j0;
    float4 a0 = *(const float4*)(p0);       // issued early, consumed late
    float4 a1 = *(const float4*)(p0 + 4);
    float4 c0 = *(const float4*)(p1);
    float4 c1 = *(const float4*)(p1 + 4);

    const unsigned int* gp = gpack + b * HWSZ + i * WW;
    unsigned int pk[8];
#pragma unroll
    for (int t = 0; t < 8; ++t) pk[t] = gp[k + 64 * t];
#pragma unroll
    for (int t = 0; t < 8; ++t) {
        int idx = k + 64 * t;
        unsigned int gN = pk[t] & 0xFFFFu;
        unsigned int gP = pk[t] >> 16;
        g2n[SK(idx)] = (gN == 0xFFFFu) ? 1e18f : (float)(gN * gN);
        g2p[SK(idx)] = (gP == 0xFFFFu) ? 1e18f : (float)(gP * gP);
    }
    __syncthreads();

    float bn[8], bp[8];
#pragma unroll
    for (int jj = 0; jj < 8; ++jj) {
        bn[jj] = g2n[SK(j0 + jj)];
        bp[jj] = g2p[SK(j0 + jj)];
    }
    for (int r = 1; r < WW; ++r) {
        float sq = (float)(r * r);
        float mx = 0.0f;
#pragma unroll
        for (int jj = 0; jj < 8; ++jj) mx = fmaxf(mx, fmaxf(bn[jj], bp[jj]));
        if (sq >= mx) break;        // all 8 columns of this lane converged
#pragma unroll
        for (int jj = 0; jj < 8; ++jj) {
            int kl = j0 + jj - r; kl = kl < 0 ? 0 : kl;
            int kr = j0 + jj + r; kr = kr > (WW - 1) ? (WW - 1) : kr;
            int skl = SK(kl), skr = SK(kr);
            bn[jj] = fminf(bn[jj], sq + g2n[skl]);
            bp[jj] = fminf(bp[jj], sq + g2p[skl]);
            bn[jj] = fminf(bn[jj], sq + g2n[skr]);
            bp[jj] = fminf(bp[jj], sq + g2p[skr]);
        }
    }

    float x0[8] = {a0.x, a0.y, a0.z, a0.w, a1.x, a1.y, a1.z, a1.w};
    float x1[8] = {c0.x, c0.y, c0.z, c0.w, c1.x, c1.y, c1.z, c1.w};
    float acc = 0.0f;
#pragma unroll
    for (int jj = 0; jj < 8; ++jj) {
        float dist = sqrtf(bn[jj]) - sqrtf(bp[jj]);          // negEDT - posEDT
        float prob = 1.0f / (1.0f + __expf(x0[jj] - x1[jj]));  // softmax class-1
        acc += prob * dist;
    }
#pragma unroll
    for (int off = 32; off > 0; off >>= 1) acc += __shfl_down(acc, off, 64);
    if (k == 0) partials[bi] = (double)acc;
}

__global__ __launch_bounds__(256) void finalize_kernel(
    const int* __restrict__ counts,
    const double* __restrict__ partials,
    float* __restrict__ out)
{
    __shared__ double red[256];
    __shared__ int pres[BB];
    int tid = threadIdx.x;

    if (tid < BB) pres[tid] = 0;
    __syncthreads();
    if (tid < COLS_BLOCKS && counts[tid] > 0)
        atomicOr(&pres[tid >> 5], 1);          // 32 cols-blocks per batch
    __syncthreads();

    double s = 0.0;
    for (int idx = tid; idx < ROWS_BLOCKS; idx += 256)
        s += pres[idx >> 9] ? partials[idx] : 0.0;  // 'if mask.sum() > 0'
    red[tid] = s;
    __syncthreads();
    for (int off = 128; off > 0; off >>= 1) {
        if (tid < off) red[tid] += red[tid + off];
        __syncthreads();
    }
    if (tid == 0)
        out[0] = (float)(red[0] * (1.0 / 2097152.0));  // mean over B*C*H*W
}

extern "C" void kernel_launch(void* const* d_in, const int* in_sizes, int n_in,
                              void* d_out, int out_size, void* d_ws, size_t ws_size,
                              hipStream_t stream) {
    const float* pred = (const float*)d_in[0];
    const int* target = (const int*)d_in[1];
    float* out = (float*)d_out;

    char* ws = (char*)d_ws;
    int* counts = (int*)(ws + 0);
    double* partials = (double*)(ws + 1024);
    unsigned int* gpack = (unsigned int*)(ws + 32768);

    edt_cols_kernel<<<COLS_BLOCKS, 512, 0, stream>>>(target, gpack, counts);
    edt_rows_kernel<<<ROWS_BLOCKS, 64, 0, stream>>>(gpack, pred, partials);
    finalize_kernel<<<1, 256, 0, stream>>>(counts, partials, out);
}